// Round 1
// baseline (75.229 us; speedup 1.0000x reference)
//
#include <hip/hip_runtime.h>

// QuantumFeatureMap, N_QUBITS=4, ALPHA=1.57.
// Closed form derivation:
//   After RY layer the state is a product state; CNOT ring only permutes
//   computational basis states (linear over GF(2)). Each diagonal Z/ZZ
//   observable pulls back to a product of per-qubit z operators in the
//   *initial* product basis, so every expectation is a product of
//   t_q = cos(ALPHA * x_q):
//     <Z0> = t1 t2 t3      <Z1> = t0 t1
//     <Z2> = t0 t1 t2      <Z3> = t0 t1 t2 t3
//     <Z0Z1> = t0 t2 t3    <Z0Z2> = t0 t3    <Z0Z3> = t0
//     <Z1Z2> = t2          <Z1Z3> = t2 t3    <Z2Z3> = t3
// Memory-bound: 16 B in + 40 B out per row; LDS-staged coalesced stores.

#define QFM_ALPHA 1.57f

__global__ __launch_bounds__(256) void qfm_kernel(const float4* __restrict__ x,
                                                  float4* __restrict__ out4,
                                                  int B) {
    __shared__ float4 lds4[640];            // 256 rows * 10 floats = 2560 floats
    float* lds = (float*)lds4;

    int b = blockIdx.x * 256 + threadIdx.x;
    float t0 = 1.f, t1 = 1.f, t2 = 1.f, t3 = 1.f;
    if (b < B) {
        float4 v = x[b];                    // coalesced 16B/lane load
        t0 = __cosf(QFM_ALPHA * v.x);
        t1 = __cosf(QFM_ALPHA * v.y);
        t2 = __cosf(QFM_ALPHA * v.z);
        t3 = __cosf(QFM_ALPHA * v.w);
    }

    float t01 = t0 * t1;
    float t23 = t2 * t3;

    float* r = &lds[threadIdx.x * 10];      // stride 10: 2-way bank alias (free on wave64)
    r[0] = t1 * t23;        // <Z0>
    r[1] = t01;             // <Z1>
    r[2] = t01 * t2;        // <Z2>
    r[3] = t01 * t23;       // <Z3>
    r[4] = t0 * t23;        // <Z0Z1>
    r[5] = t0 * t3;         // <Z0Z2>
    r[6] = t0;              // <Z0Z3>
    r[7] = t2;              // <Z1Z2>
    r[8] = t23;             // <Z1Z3>
    r[9] = t3;              // <Z2Z3>
    __syncthreads();

    // Coalesced float4 stores of the whole block's 2560-float output slab.
    size_t base = (size_t)blockIdx.x * 640;       // in float4 units
    size_t limit = ((size_t)B * 10 + 3) / 4;      // guard for tail block (B%256==0 here anyway)
    for (int i = threadIdx.x; i < 640; i += 256) {
        size_t o = base + i;
        if (o < limit) out4[o] = lds4[i];
    }
}

extern "C" void kernel_launch(void* const* d_in, const int* in_sizes, int n_in,
                              void* d_out, int out_size, void* d_ws, size_t ws_size,
                              hipStream_t stream) {
    const float4* x = (const float4*)d_in[0];
    float4* out = (float4*)d_out;
    int B = in_sizes[0] / 4;                      // rows of [B,4]
    int grid = (B + 255) / 256;
    qfm_kernel<<<grid, 256, 0, stream>>>(x, out, B);
}

// Round 3
// 74.883 us; speedup vs baseline: 1.0046x; 1.0046x over previous
//
#include <hip/hip_runtime.h>

// QuantumFeatureMap, N_QUBITS=4, ALPHA=1.57 — closed form.
// After the RY layer the state is a product state; the CNOT ring only permutes
// basis states (GF(2)-linear), so every diagonal Z/ZZ observable pulls back to
// a product of per-qubit z's whose expectation is t_q = cos(ALPHA*x_q):
//   <Z0>=t1t2t3  <Z1>=t0t1  <Z2>=t0t1t2  <Z3>=t0t1t2t3
//   <Z0Z1>=t0t2t3 <Z0Z2>=t0t3 <Z0Z3>=t0 <Z1Z2>=t2 <Z1Z3>=t2t3 <Z2Z3>=t3
// Memory-bound: 16 B in + 40 B out per row. Wave-local LDS staging (no block
// barrier) re-packs the stride-10 row outputs into coalesced 16B stores.

#define QFM_ALPHA 1.57f

typedef float v4f __attribute__((ext_vector_type(4)));   // native vector: ok for nontemporal builtins

__global__ __launch_bounds__(256) void qfm_kernel(const v4f* __restrict__ x,
                                                  v4f* __restrict__ out4,
                                                  int B) {
    __shared__ v4f lds4[640];               // 4 waves * 160 v4f (64 rows * 10 floats each)
    float* lds = (float*)lds4;

    int tid  = threadIdx.x;
    int wave = tid >> 6;
    int lane = tid & 63;
    int b = blockIdx.x * 256 + tid;

    float t0 = 1.f, t1 = 1.f, t2 = 1.f, t3 = 1.f;
    if (b < B) {
        v4f v = x[b];                       // coalesced 16B/lane load
        t0 = __cosf(QFM_ALPHA * v.x);
        t1 = __cosf(QFM_ALPHA * v.y);
        t2 = __cosf(QFM_ALPHA * v.z);
        t3 = __cosf(QFM_ALPHA * v.w);
    }

    float t01 = t0 * t1;
    float t23 = t2 * t3;

    // Wave-local slab: lane l owns floats [l*10, l*10+10) of its wave's 640-float slab.
    float* r = &lds[wave * 640 + lane * 10];
    r[0] = t1 * t23;        // <Z0>
    r[1] = t01;             // <Z1>
    r[2] = t01 * t2;        // <Z2>
    r[3] = t01 * t23;       // <Z3>
    r[4] = t0 * t23;        // <Z0Z1>
    r[5] = t0 * t3;         // <Z0Z2>
    r[6] = t0;              // <Z0Z3>
    r[7] = t2;              // <Z1Z2>
    r[8] = t23;             // <Z1Z3>
    r[9] = t3;              // <Z2Z3>
    // No __syncthreads: the readback below only touches this wave's own slab,
    // and within-wave LDS ordering is enforced by lgkmcnt waits.

    const v4f* slab = &lds4[wave * 160];
    int base  = blockIdx.x * 640 + wave * 160;          // v4f units
    int limit = (B * 10 + 3) >> 2;                      // tail guard (exact fit when B%256==0)

    v4f v0 = slab[lane];
    v4f v1 = slab[lane + 64];
    if (base + lane      < limit) __builtin_nontemporal_store(v0, &out4[base + lane]);
    if (base + lane + 64 < limit) __builtin_nontemporal_store(v1, &out4[base + lane + 64]);
    if (lane < 32) {
        v4f v2 = slab[lane + 128];
        if (base + lane + 128 < limit) __builtin_nontemporal_store(v2, &out4[base + lane + 128]);
    }
}

extern "C" void kernel_launch(void* const* d_in, const int* in_sizes, int n_in,
                              void* d_out, int out_size, void* d_ws, size_t ws_size,
                              hipStream_t stream) {
    const v4f* x = (const v4f*)d_in[0];
    v4f* out = (v4f*)d_out;
    int B = in_sizes[0] / 4;                      // rows of [B,4]
    int grid = (B + 255) / 256;
    qfm_kernel<<<grid, 256, 0, stream>>>(x, out, B);
}